// Round 2
// baseline (389.952 us; speedup 1.0000x reference)
//
#include <hip/hip_runtime.h>

#define K_TAGS 128
#define T_MAX  512
#define N_SEQ  512
#define START_TAG 126
#define END_TAG   127
#define LOG2E 1.44269504088896340736f
#define LN2   0.69314718055994530942f

__device__ __forceinline__ float fexp2(float x) {
#if __has_builtin(__builtin_amdgcn_exp2f)
  return __builtin_amdgcn_exp2f(x);
#else
  return exp2f(x);
#endif
}
__device__ __forceinline__ float flog2(float x) {
#if __has_builtin(__builtin_amdgcn_logf)
  return __builtin_amdgcn_logf(x);
#else
  return __log2f(x);
#endif
}

// Raw barrier: drain LDS only (NOT vmcnt) so global f-prefetch stays in
// flight across steps (m201 pattern). The trailing empty asm is the
// codegen fence keeping post-barrier LDS reads below the barrier.
__device__ __forceinline__ void lds_barrier() {
  asm volatile("s_waitcnt lgkmcnt(0)" ::: "memory");
  __builtin_amdgcn_s_barrier();
  asm volatile("" ::: "memory");
}

// One block per sequence, 256 threads = 4 waves.
// Lane (jg=tid>>2, q=tid&3) owns columns {jg, jg+64}, rows [32q,32q+32).
// Work in base-2 log domain; E=2^(trans*log2e) in registers (64/lane),
// rows traversed in order c^(2q) so the 4 q-groups hit disjoint LDS banks.
// Per step (1 barrier): read p from LDS, 64 FMAs, combine via 2+2 shfl_xor,
// p_next = acc * 2^(f*log2e + Ncur - Nnxt)  [no log2->exp2 on the path],
// normalizer N = lane0's alpha(col0), published through LDS, 1-step stale
// (safe: alpha spread+drift << 126 in log2 units; logsumexp contracts).
__global__ __launch_bounds__(256, 2) void crf_fwd_kernel(
    const float* __restrict__ feats,    // [B, T, K]
    const float* __restrict__ trans,    // [K, K]
    const int*   __restrict__ lengths,  // [B]
    float*       __restrict__ partial)  // [B]
{
  const int blk = blockIdx.x;
  // LPT pairing: blocks c and c+256 co-reside on a CU under round-robin
  // dispatch; pair longest with shortest (lengths are sorted descending).
  const int b   = (blk < N_SEQ / 2) ? blk : (3 * N_SEQ / 2 - 1 - blk);
  const int tid = (int)threadIdx.x;
  const int jg  = tid >> 2;          // 0..63
  const int q   = tid & 3;           // i-quarter
  const int j0  = jg;
  const int j1  = jg + 64;
  const int i0  = q * 32;

  const int len = lengths[b];
  const float* fb = feats + (size_t)b * (T_MAX * K_TAGS);

  __shared__ __align__(16) float p_sh[2][K_TAGS];
  __shared__ float nrm[2];
  __shared__ float red[8];

  // E in registers, rows in XOR-swizzled order (bank-conflict-free reads).
  // E index 4c+m is compile-time constant (rule #20: no runtime indexing).
  float E0[32], E1[32];
#pragma unroll
  for (int c = 0; c < 8; ++c) {
    const int r = i0 + 4 * (c ^ (q << 1));
#pragma unroll
    for (int m = 0; m < 4; ++m) {
      E0[4 * c + m] = fexp2(trans[(r + m) * K_TAGS + j0] * LOG2E);
      E1[4 * c + m] = fexp2(trans[(r + m) * K_TAGS + j1] * LOG2E);
    }
  }

  // p(0) = 2^(alpha_init - 0): 1 at START, exp2(-14427)->0 elsewhere.
  if (q == 0) {
    p_sh[0][j0] = (j0 == START_TAG) ? 1.0f : 0.0f;
    p_sh[0][j1] = (j1 == START_TAG) ? 1.0f : 0.0f;
  }
  if (tid == 0) nrm[0] = 0.0f;  // N_1 (col-0 init is degenerate; use 0)

  float a0 = (j0 == START_TAG) ? 0.0f : -10000.0f * LOG2E;
  float a1 = (j1 == START_TAG) ? 0.0f : -10000.0f * LOG2E;
  float Ncur = 0.0f;  // N_0

  // depth-2 feats prefetch (rides across raw barriers)
  float f0cur = fb[j0];
  float f1cur = fb[j1];
  const int t1 = (len > 1) ? 1 : 0;
  float f0nx = fb[t1 * K_TAGS + j0];
  float f1nx = fb[t1 * K_TAGS + j1];

  for (int t = 0; t < len; ++t) {
    const int buf = t & 1;
    // issue loads for t+2 now; consumed two barriers later
    const int tp = (t + 2 < len) ? (t + 2) : (len - 1);
    const float nf0 = fb[tp * K_TAGS + j0];
    const float nf1 = fb[tp * K_TAGS + j1];

    lds_barrier();  // p_sh[buf], nrm[buf] (written end of t-1) now visible

    const float Nnxt = nrm[buf];  // N_{t+1}

    // matvec partials over my 32 rows, both columns, swizzled chunk order
    const float* pp = p_sh[buf];
    float s00 = 0.f, s01 = 0.f, s02 = 0.f, s03 = 0.f;
    float s10 = 0.f, s11 = 0.f, s12 = 0.f, s13 = 0.f;
#pragma unroll
    for (int c = 0; c < 8; ++c) {
      const int w0 = i0 + 4 * (c ^ (q << 1));
      const float4 pv = *reinterpret_cast<const float4*>(pp + w0);
      s00 = fmaf(pv.x, E0[4 * c + 0], s00);
      s01 = fmaf(pv.y, E0[4 * c + 1], s01);
      s02 = fmaf(pv.z, E0[4 * c + 2], s02);
      s03 = fmaf(pv.w, E0[4 * c + 3], s03);
      s10 = fmaf(pv.x, E1[4 * c + 0], s10);
      s11 = fmaf(pv.y, E1[4 * c + 1], s11);
      s12 = fmaf(pv.z, E1[4 * c + 2], s12);
      s13 = fmaf(pv.w, E1[4 * c + 3], s13);
    }
    float acc0 = (s00 + s01) + (s02 + s03);
    float acc1 = (s10 + s11) + (s12 + s13);
    acc0 += __shfl_xor(acc0, 1, 64);
    acc0 += __shfl_xor(acc0, 2, 64);
    acc1 += __shfl_xor(acc1, 1, 64);
    acc1 += __shfl_xor(acc1, 2, 64);

    // p_next = acc * 2^(f*log2e + Ncur - Nnxt)  == 2^(a_new - Nnxt) exactly
    const float d  = Ncur - Nnxt;
    const float g0 = fexp2(fmaf(f0cur, LOG2E, d));
    const float g1 = fexp2(fmaf(f1cur, LOG2E, d));
    const float p0 = acc0 * g0;
    const float p1 = acc1 * g1;

    // alpha maintained off the critical path (final logsumexp + N publish)
    a0 = fmaf(f0cur, LOG2E, Ncur + flog2(acc0));
    a1 = fmaf(f1cur, LOG2E, Ncur + flog2(acc1));

    if (q < 2) p_sh[buf ^ 1][(q == 0) ? j0 : j1] = (q == 0) ? p0 : p1;
    if (tid == 0) nrm[buf ^ 1] = a0;  // N_{t+2} = alpha_col0(t+1)

    Ncur = Nnxt;
    f0cur = f0nx; f1cur = f1nx;
    f0nx = nf0;   f1nx = nf1;
  }

  __syncthreads();  // full drain once; separates loop LDS from final reduce

  // final = alpha + trans[:,END]*log2e ; per-sequence logsumexp (base 2).
  // a0/a1 are identical across the 4 q-lanes (post-shfl combine).
  const float fin0 = a0 + trans[j0 * K_TAGS + END_TAG] * LOG2E;
  const float fin1 = a1 + trans[j1 * K_TAGS + END_TAG] * LOG2E;

  float m = fmaxf(fin0, fin1);
#pragma unroll
  for (int off = 4; off < 64; off <<= 1)
    m = fmaxf(m, __shfl_xor(m, off, 64));
  if ((tid & 63) == 0) red[tid >> 6] = m;
  __syncthreads();
  const float Mf = fmaxf(fmaxf(red[0], red[1]), fmaxf(red[2], red[3]));

  float e = (q == 0) ? (fexp2(fin0 - Mf) + fexp2(fin1 - Mf)) : 0.0f;
#pragma unroll
  for (int off = 1; off < 64; off <<= 1)
    e += __shfl_xor(e, off, 64);
  if ((tid & 63) == 0) red[4 + (tid >> 6)] = e;
  __syncthreads();
  if (tid == 0) {
    const float s = (red[4] + red[5]) + (red[6] + red[7]);
    partial[b] = (Mf + flog2(s)) * LN2;  // back to natural log
  }
}

// Deterministic reduction of the 512 per-sequence results.
__global__ void crf_reduce(const float* __restrict__ partial,
                           float* __restrict__ out) {
  const int tid = (int)threadIdx.x;  // 256 threads
  float s = partial[tid] + partial[tid + 256];
#pragma unroll
  for (int off = 1; off < 64; off <<= 1) s += __shfl_xor(s, off, 64);
  __shared__ float ws[4];
  if ((tid & 63) == 0) ws[tid >> 6] = s;
  __syncthreads();
  if (tid == 0) out[0] = (ws[0] + ws[1]) + (ws[2] + ws[3]);
}

extern "C" void kernel_launch(void* const* d_in, const int* in_sizes, int n_in,
                              void* d_out, int out_size, void* d_ws, size_t ws_size,
                              hipStream_t stream) {
  const float* feats   = (const float*)d_in[0];
  const float* trans   = (const float*)d_in[1];
  const int*   lengths = (const int*)d_in[2];
  float* partial = (float*)d_ws;   // 512 floats of scratch
  float* out     = (float*)d_out;  // single f32

  crf_fwd_kernel<<<dim3(N_SEQ), dim3(256), 0, stream>>>(feats, trans, lengths, partial);
  crf_reduce<<<dim3(1), dim3(256), 0, stream>>>(partial, out);
}

// Round 3
// 335.730 us; speedup vs baseline: 1.1615x; 1.1615x over previous
//
#include <hip/hip_runtime.h>

#define K_TAGS 128
#define T_MAX  512
#define N_SEQ  512
#define START_TAG 126
#define END_TAG   127
#define LOG2E 1.44269504088896340736f
#define LN2   0.69314718055994530942f

typedef float v2f __attribute__((ext_vector_type(2)));

__device__ __forceinline__ float fexp2(float x) { return exp2f(x); }
__device__ __forceinline__ float flog2(float x) { return __log2f(x); }

// Quad-local butterfly via DPP quad_perm: 0xB1 = xor1 {1,0,3,2},
// 0x4E = xor2 {2,3,0,1}. VALU latency, replaces ds-pipe shuffles.
template <int CTRL>
__device__ __forceinline__ float dpp_swap(float x) {
  return __int_as_float(__builtin_amdgcn_update_dpp(
      0, __float_as_int(x), CTRL, 0xF, 0xF, true));
}

// Raw barrier: drain LDS only (NOT vmcnt) so global f-prefetch stays in
// flight across steps.
__device__ __forceinline__ void lds_barrier() {
  asm volatile("s_waitcnt lgkmcnt(0)" ::: "memory");
  __builtin_amdgcn_s_barrier();
  asm volatile("" ::: "memory");
}

// One block per sequence, 256 threads = 4 waves.
// Lane (jg=tid>>2, q=tid&3) owns columns {jg, jg+64}, rows [32q,32q+32).
// Base-2 log domain; E = 2^(trans*log2e) in registers as float2 pairs
// (v_pk_fma_f32), rows chunk-ordered c^(2q) -> conflict-free LDS reads.
// Per step (1 barrier): read p (b128), 32 pk_fma, DPP quad butterfly,
// p_next = acc * 2^(f*log2e + Ncur - Nnxt) (exp2 computed in FMA shadow),
// normalizer N = col-0 alpha published via LDS, 1 step stale (safe:
// log2-domain spread+drift << 126; logsumexp contracts).
__global__ __launch_bounds__(256, 2) void crf_fwd_kernel(
    const float* __restrict__ feats,    // [B, T, K]
    const float* __restrict__ trans,    // [K, K]
    const int*   __restrict__ lengths,  // [B]
    float*       __restrict__ partial)  // [B]
{
  const int blk = blockIdx.x;
  // LPT pairing: blocks c and c+256 co-reside on a CU (round-robin over
  // 8 XCDs x 32 CUs); pair longest with shortest (lengths sorted desc).
  const int b   = (blk < N_SEQ / 2) ? blk : (3 * N_SEQ / 2 - 1 - blk);
  const int tid = (int)threadIdx.x;
  const int jg  = tid >> 2;          // 0..63
  const int q   = tid & 3;           // row-quarter within the quad
  const int j0  = jg;
  const int j1  = jg + 64;
  const int i0  = q * 32;

  const int len = lengths[b];
  const float* fb = feats + (size_t)b * (T_MAX * K_TAGS);

  __shared__ __align__(16) float p_sh[2][K_TAGS];
  __shared__ float nrm[2];
  __shared__ float red[8];

  // E in registers as float2 row-pairs, chunk order c^(2q) (bank swizzle).
  // All indices compile-time constant (no scratch).
  v2f E0[16], E1[16];
#pragma unroll
  for (int c = 0; c < 8; ++c) {
    const int r = i0 + 4 * (c ^ (q << 1));
    E0[2 * c + 0] = v2f{fexp2(trans[(r + 0) * K_TAGS + j0] * LOG2E),
                        fexp2(trans[(r + 1) * K_TAGS + j0] * LOG2E)};
    E0[2 * c + 1] = v2f{fexp2(trans[(r + 2) * K_TAGS + j0] * LOG2E),
                        fexp2(trans[(r + 3) * K_TAGS + j0] * LOG2E)};
    E1[2 * c + 0] = v2f{fexp2(trans[(r + 0) * K_TAGS + j1] * LOG2E),
                        fexp2(trans[(r + 1) * K_TAGS + j1] * LOG2E)};
    E1[2 * c + 1] = v2f{fexp2(trans[(r + 2) * K_TAGS + j1] * LOG2E),
                        fexp2(trans[(r + 3) * K_TAGS + j1] * LOG2E)};
  }

  // p(0) = 2^(alpha_init - 0): 1 at START, 0 elsewhere.
  if (q == 0) {
    p_sh[0][j0] = (j0 == START_TAG) ? 1.0f : 0.0f;
    p_sh[0][j1] = (j1 == START_TAG) ? 1.0f : 0.0f;
  }
  if (tid == 0) nrm[0] = 0.0f;

  float a0 = (j0 == START_TAG) ? 0.0f : -10000.0f * LOG2E;
  float a1 = (j1 == START_TAG) ? 0.0f : -10000.0f * LOG2E;
  float Ncur = 0.0f;

  // depth-2 feats prefetch (rides across lgkm-only barriers)
  float f0cur = fb[j0];
  float f1cur = fb[j1];
  const int t1 = (len > 1) ? 1 : 0;
  float f0nx = fb[t1 * K_TAGS + j0];
  float f1nx = fb[t1 * K_TAGS + j1];

#define STEP(BUF, TT)                                                        \
  {                                                                          \
    const int tp = ((TT) + 2 < len) ? ((TT) + 2) : (len - 1);                \
    const float nf0 = fb[tp * K_TAGS + j0];                                  \
    const float nf1 = fb[tp * K_TAGS + j1];                                  \
    lds_barrier();                                                           \
    const float Nnxt = nrm[BUF];                                             \
    const float d  = Ncur - Nnxt;                                            \
    const float g0 = fexp2(fmaf(f0cur, LOG2E, d));                           \
    const float g1 = fexp2(fmaf(f1cur, LOG2E, d));                           \
    const float* pp = p_sh[BUF];                                             \
    v2f s0a = {0.f, 0.f}, s0b = {0.f, 0.f};                                  \
    v2f s1a = {0.f, 0.f}, s1b = {0.f, 0.f};                                  \
    _Pragma("unroll")                                                        \
    for (int c = 0; c < 8; ++c) {                                            \
      const int w0 = i0 + 4 * (c ^ (q << 1));                                \
      const float4 pv = *reinterpret_cast<const float4*>(pp + w0);           \
      const v2f pA = {pv.x, pv.y};                                           \
      const v2f pB = {pv.z, pv.w};                                           \
      s0a = __builtin_elementwise_fma(pA, E0[2 * c + 0], s0a);               \
      s0b = __builtin_elementwise_fma(pB, E0[2 * c + 1], s0b);               \
      s1a = __builtin_elementwise_fma(pA, E1[2 * c + 0], s1a);               \
      s1b = __builtin_elementwise_fma(pB, E1[2 * c + 1], s1b);               \
    }                                                                        \
    const v2f s0 = s0a + s0b;                                                \
    const v2f s1 = s1a + s1b;                                                \
    float acc0 = s0.x + s0.y;                                                \
    float acc1 = s1.x + s1.y;                                                \
    acc0 += dpp_swap<0xB1>(acc0);                                            \
    acc0 += dpp_swap<0x4E>(acc0);                                            \
    acc1 += dpp_swap<0xB1>(acc1);                                            \
    acc1 += dpp_swap<0x4E>(acc1);                                            \
    const float p0 = acc0 * g0;                                              \
    const float p1 = acc1 * g1;                                              \
    if (q < 2) p_sh[(BUF) ^ 1][(q == 0) ? j0 : j1] = (q == 0) ? p0 : p1;     \
    a0 = fmaf(f0cur, LOG2E, Ncur + flog2(acc0));                             \
    a1 = fmaf(f1cur, LOG2E, Ncur + flog2(acc1));                             \
    if (tid == 0) nrm[(BUF) ^ 1] = a0;                                       \
    Ncur = Nnxt;                                                             \
    f0cur = f0nx; f1cur = f1nx;                                              \
    f0nx = nf0;   f1nx = nf1;                                                \
  }

  int t = 0;
  for (; t + 2 <= len; t += 2) {
    STEP(0, t)
    STEP(1, t + 1)
  }
  if (t < len) STEP(0, t)
#undef STEP

  __syncthreads();  // full drain once; separates loop LDS from final reduce

  // final = alpha + trans[:,END]*log2e ; per-sequence logsumexp (base 2).
  // a0/a1 identical across the 4 quad lanes (post-butterfly).
  const float fin0 = a0 + trans[j0 * K_TAGS + END_TAG] * LOG2E;
  const float fin1 = a1 + trans[j1 * K_TAGS + END_TAG] * LOG2E;

  float m = fmaxf(fin0, fin1);
#pragma unroll
  for (int off = 4; off < 64; off <<= 1)
    m = fmaxf(m, __shfl_xor(m, off, 64));
  if ((tid & 63) == 0) red[tid >> 6] = m;
  __syncthreads();
  const float Mf = fmaxf(fmaxf(red[0], red[1]), fmaxf(red[2], red[3]));

  float e = (q == 0) ? (fexp2(fin0 - Mf) + fexp2(fin1 - Mf)) : 0.0f;
#pragma unroll
  for (int off = 1; off < 64; off <<= 1)
    e += __shfl_xor(e, off, 64);
  if ((tid & 63) == 0) red[4 + (tid >> 6)] = e;
  __syncthreads();
  if (tid == 0) {
    const float s = (red[4] + red[5]) + (red[6] + red[7]);
    partial[b] = (Mf + flog2(s)) * LN2;  // back to natural log
  }
}

// Deterministic reduction of the 512 per-sequence results.
__global__ void crf_reduce(const float* __restrict__ partial,
                           float* __restrict__ out) {
  const int tid = (int)threadIdx.x;  // 256 threads
  float s = partial[tid] + partial[tid + 256];
#pragma unroll
  for (int off = 1; off < 64; off <<= 1) s += __shfl_xor(s, off, 64);
  __shared__ float ws[4];
  if ((tid & 63) == 0) ws[tid >> 6] = s;
  __syncthreads();
  if (tid == 0) out[0] = (ws[0] + ws[1]) + (ws[2] + ws[3]);
}

extern "C" void kernel_launch(void* const* d_in, const int* in_sizes, int n_in,
                              void* d_out, int out_size, void* d_ws, size_t ws_size,
                              hipStream_t stream) {
  const float* feats   = (const float*)d_in[0];
  const float* trans   = (const float*)d_in[1];
  const int*   lengths = (const int*)d_in[2];
  float* partial = (float*)d_ws;   // 512 floats of scratch
  float* out     = (float*)d_out;  // single f32

  crf_fwd_kernel<<<dim3(N_SEQ), dim3(256), 0, stream>>>(feats, trans, lengths, partial);
  crf_reduce<<<dim3(1), dim3(256), 0, stream>>>(partial, out);
}

// Round 4
// 324.754 us; speedup vs baseline: 1.2008x; 1.0338x over previous
//
#include <hip/hip_runtime.h>

#define K_TAGS 128
#define T_MAX  512
#define N_SEQ  512
#define START_TAG 126
#define END_TAG   127
#define LOG2E 1.44269504088896340736f
#define LN2   0.69314718055994530942f

typedef float v2f __attribute__((ext_vector_type(2)));

__device__ __forceinline__ float fexp2(float x) {
#if __has_builtin(__builtin_amdgcn_exp2f)
  return __builtin_amdgcn_exp2f(x);
#else
  return exp2f(x);
#endif
}
__device__ __forceinline__ float flog2(float x) {
#if __has_builtin(__builtin_amdgcn_logf)
  return __builtin_amdgcn_logf(x);
#else
  return __log2f(x);
#endif
}

// DPP helpers. quad_perm 0xB1 = xor1, 0x4E = xor2 (sum butterfly within a
// quad). row_ror:4 = 0x124, row_ror:8 = 0x128 (max over the 16-lane row:
// valid because quad lanes hold identical values, so {l,l+4,l+8,l+12}
// covers all four quads).
template <int CTRL>
__device__ __forceinline__ float dpp_mov(float x) {
  return __int_as_float(__builtin_amdgcn_update_dpp(
      0, __float_as_int(x), CTRL, 0xF, 0xF, true));
}

// LDS-only barrier: drains lgkmcnt, NOT vmcnt, so the depth-4 global
// feats prefetch stays in flight across steps.
__device__ __forceinline__ void lds_barrier() {
  asm volatile("s_waitcnt lgkmcnt(0)" ::: "memory");
  __builtin_amdgcn_s_barrier();
  asm volatile("" ::: "memory");
}

// One block per sequence, 256 threads = 4 waves.
// Lane (jg=tid>>2, q=tid&3) owns columns {jg, jg+64}, rows [32q,32q+32).
// LINEAR domain: invariant  alpha2_j(t) = log2(p_t[j]) + C.
// Per step: acc_j = sum_i p[i]*E2[i][j]  (E2 = 2^(trans*log2e), registers),
//           p' = acc * 2^(f*log2e - D)   (g computed off the critical path),
// D published every 2 steps from the true max of p (DPP row_ror maxes ->
// 16 LDS slots -> broadcast read + log2). No per-step log2/exp2 on the
// recurrence path. One lgkm-only barrier per step.
__global__ __launch_bounds__(256, 2) void crf_fwd_kernel(
    const float* __restrict__ feats,    // [B, T, K]
    const float* __restrict__ trans,    // [K, K]
    const int*   __restrict__ lengths,  // [B]
    float*       __restrict__ partial)  // [B]
{
  const int blk = blockIdx.x;
  // LPT pairing: blocks c and c+256 co-reside on a CU under round-robin
  // dispatch; pair longest with shortest (lengths sorted descending).
  const int b   = (blk < N_SEQ / 2) ? blk : (3 * N_SEQ / 2 - 1 - blk);
  const int tid = (int)threadIdx.x;
  const int jg  = tid >> 2;
  const int q   = tid & 3;
  const int j0  = jg;
  const int j1  = jg + 64;
  const int i0  = q * 32;

  const int len = lengths[b];
  const float* fb = feats + (size_t)b * (T_MAX * K_TAGS);

  __shared__ __align__(16) float p_sh[2][K_TAGS];
  __shared__ __align__(16) float red16[16];
  __shared__ float red8[8];

  // E2 in registers as float2 row-pairs, chunk order c^(2q) (bank swizzle).
  // All indices compile-time constant.
  v2f E0[16], E1[16];
#pragma unroll
  for (int c = 0; c < 8; ++c) {
    const int r = i0 + 4 * (c ^ (q << 1));
    E0[2 * c + 0] = v2f{fexp2(trans[(r + 0) * K_TAGS + j0] * LOG2E),
                        fexp2(trans[(r + 1) * K_TAGS + j0] * LOG2E)};
    E0[2 * c + 1] = v2f{fexp2(trans[(r + 2) * K_TAGS + j0] * LOG2E),
                        fexp2(trans[(r + 3) * K_TAGS + j0] * LOG2E)};
    E1[2 * c + 0] = v2f{fexp2(trans[(r + 0) * K_TAGS + j1] * LOG2E),
                        fexp2(trans[(r + 1) * K_TAGS + j1] * LOG2E)};
    E1[2 * c + 1] = v2f{fexp2(trans[(r + 2) * K_TAGS + j1] * LOG2E),
                        fexp2(trans[(r + 3) * K_TAGS + j1] * LOG2E)};
  }

  // p(0) = onehot(START)
  if (q == 0) {
    p_sh[0][j0] = (j0 == START_TAG) ? 1.0f : 0.0f;
    p_sh[0][j1] = (j1 == START_TAG) ? 1.0f : 0.0f;
  }

  float Cc  = 0.0f;            // cumulative log2 normalizer (block-uniform)
  float pc0 = 0.0f, pc1 = 0.0f;  // final-step p values (persist)

  // depth-4 prefetch: four named register sets, no rotation copies.
  float fA0, fA1, fB0, fB1, fC0, fC1, fD0, fD1;
  {
    const int tB = (len > 1) ? 1 : 0;
    const int tC = (len > 2) ? 2 : (len - 1);
    const int tD = (len > 3) ? 3 : (len - 1);
    fA0 = fb[j0];                fA1 = fb[j1];
    fB0 = fb[tB * K_TAGS + j0];  fB1 = fb[tB * K_TAGS + j1];
    fC0 = fb[tC * K_TAGS + j0];  fC1 = fb[tC * K_TAGS + j1];
    fD0 = fb[tD * K_TAGS + j0];  fD1 = fb[tD * K_TAGS + j1];
  }

#define BODY(BUF, F0, F1, ODD, TT)                                           \
  {                                                                          \
    const float fl0 = F0, fl1 = F1; /* load issued 4 bodies ago: done */     \
    const int tp = ((TT) + 4 < len) ? ((TT) + 4) : (len - 1);                \
    F0 = fb[tp * K_TAGS + j0]; /* issue t+4 loads; consumed 4 bodies on */   \
    F1 = fb[tp * K_TAGS + j1];                                               \
    lds_barrier();                                                           \
    float D = 0.0f;                                                          \
    if (ODD) { /* rescale: broadcast-read 16 maxes published last step */    \
      const float4 r0 = *reinterpret_cast<const float4*>(&red16[0]);         \
      const float4 r1 = *reinterpret_cast<const float4*>(&red16[4]);         \
      const float4 r2 = *reinterpret_cast<const float4*>(&red16[8]);         \
      const float4 r3 = *reinterpret_cast<const float4*>(&red16[12]);        \
      float mm = fmaxf(fmaxf(fmaxf(r0.x, r0.y), fmaxf(r0.z, r0.w)),          \
                       fmaxf(fmaxf(r1.x, r1.y), fmaxf(r1.z, r1.w)));         \
      mm = fmaxf(mm, fmaxf(fmaxf(fmaxf(r2.x, r2.y), fmaxf(r2.z, r2.w)),     \
                           fmaxf(fmaxf(r3.x, r3.y), fmaxf(r3.z, r3.w))));   \
      D = flog2(mm);                                                         \
      Cc += D;                                                               \
    }                                                                        \
    const float* pp = p_sh[BUF];                                             \
    v2f s0a = {0.f, 0.f}, s0b = {0.f, 0.f};                                  \
    v2f s1a = {0.f, 0.f}, s1b = {0.f, 0.f};                                  \
    _Pragma("unroll")                                                        \
    for (int c = 0; c < 8; ++c) {                                            \
      const int w0 = i0 + 4 * (c ^ (q << 1));                                \
      const float4 pv = *reinterpret_cast<const float4*>(pp + w0);           \
      const v2f pA = {pv.x, pv.y};                                           \
      const v2f pB = {pv.z, pv.w};                                           \
      s0a = __builtin_elementwise_fma(pA, E0[2 * c + 0], s0a);               \
      s0b = __builtin_elementwise_fma(pB, E0[2 * c + 1], s0b);               \
      s1a = __builtin_elementwise_fma(pA, E1[2 * c + 0], s1a);               \
      s1b = __builtin_elementwise_fma(pB, E1[2 * c + 1], s1b);               \
    }                                                                        \
    const v2f s0 = s0a + s0b;                                                \
    const v2f s1 = s1a + s1b;                                                \
    float acc0 = s0.x + s0.y;                                                \
    float acc1 = s1.x + s1.y;                                                \
    acc0 += dpp_mov<0xB1>(acc0);                                             \
    acc0 += dpp_mov<0x4E>(acc0);                                             \
    acc1 += dpp_mov<0xB1>(acc1);                                             \
    acc1 += dpp_mov<0x4E>(acc1);                                             \
    const float g0 = fexp2(fmaf(fl0, LOG2E, -D)); /* off critical path */    \
    const float g1 = fexp2(fmaf(fl1, LOG2E, -D));                            \
    pc0 = acc0 * g0;                                                         \
    pc1 = acc1 * g1;                                                         \
    if (q < 2) p_sh[(BUF) ^ 1][(q == 0) ? j0 : j1] = (q == 0) ? pc0 : pc1;   \
    if (!(ODD)) { /* publish 16 partial maxes for next step's rescale */     \
      float mx = fmaxf(pc0, pc1);                                            \
      mx = fmaxf(mx, dpp_mov<0x124>(mx));                                    \
      mx = fmaxf(mx, dpp_mov<0x128>(mx));                                    \
      if ((tid & 15) == 0) red16[tid >> 4] = mx;                             \
    }                                                                        \
  }

  int t = 0;
  for (; t + 4 <= len; t += 4) {
    BODY(0, fA0, fA1, 0, t)
    BODY(1, fB0, fB1, 1, t + 1)
    BODY(0, fC0, fC1, 0, t + 2)
    BODY(1, fD0, fD1, 1, t + 3)
  }
  const int rem = len - t;  // block-uniform
  if (rem > 0) BODY(0, fA0, fA1, 0, t)
  if (rem > 1) BODY(1, fB0, fB1, 1, t + 1)
  if (rem > 2) BODY(0, fC0, fC1, 0, t + 2)
#undef BODY

  // Epilogue: alpha2_j = log2(p_j) + Cc; add END transition, logsumexp.
  // pc0/pc1 identical across the 4 quad lanes. p=0 -> -inf -> contributes 0.
  const float fin0 = flog2(pc0) + Cc + trans[j0 * K_TAGS + END_TAG] * LOG2E;
  const float fin1 = flog2(pc1) + Cc + trans[j1 * K_TAGS + END_TAG] * LOG2E;

  float m = fmaxf(fin0, fin1);
#pragma unroll
  for (int off = 4; off < 64; off <<= 1)
    m = fmaxf(m, __shfl_xor(m, off, 64));
  if ((tid & 63) == 0) red8[tid >> 6] = m;
  __syncthreads();
  const float Mf = fmaxf(fmaxf(red8[0], red8[1]), fmaxf(red8[2], red8[3]));

  float e = (q == 0) ? (fexp2(fin0 - Mf) + fexp2(fin1 - Mf)) : 0.0f;
#pragma unroll
  for (int off = 1; off < 64; off <<= 1)
    e += __shfl_xor(e, off, 64);
  if ((tid & 63) == 0) red8[4 + (tid >> 6)] = e;
  __syncthreads();
  if (tid == 0) {
    const float s = (red8[4] + red8[5]) + (red8[6] + red8[7]);
    partial[b] = (Mf + flog2(s)) * LN2;  // back to natural log
  }
}

// Deterministic reduction of the 512 per-sequence results.
__global__ void crf_reduce(const float* __restrict__ partial,
                           float* __restrict__ out) {
  const int tid = (int)threadIdx.x;  // 256 threads
  float s = partial[tid] + partial[tid + 256];
#pragma unroll
  for (int off = 1; off < 64; off <<= 1) s += __shfl_xor(s, off, 64);
  __shared__ float ws[4];
  if ((tid & 63) == 0) ws[tid >> 6] = s;
  __syncthreads();
  if (tid == 0) out[0] = (ws[0] + ws[1]) + (ws[2] + ws[3]);
}

extern "C" void kernel_launch(void* const* d_in, const int* in_sizes, int n_in,
                              void* d_out, int out_size, void* d_ws, size_t ws_size,
                              hipStream_t stream) {
  const float* feats   = (const float*)d_in[0];
  const float* trans   = (const float*)d_in[1];
  const int*   lengths = (const int*)d_in[2];
  float* partial = (float*)d_ws;   // 512 floats of scratch
  float* out     = (float*)d_out;  // single f32

  crf_fwd_kernel<<<dim3(N_SEQ), dim3(256), 0, stream>>>(feats, trans, lengths, partial);
  crf_reduce<<<dim3(1), dim3(256), 0, stream>>>(partial, out);
}